// Round 9
// baseline (429.663 us; speedup 1.0000x reference)
//
#include <hip/hip_runtime.h>

// Child-Sum Tree-LSTM, 16 trees x branch4 x depth8, HIDDEN=IN_DIM=128.
// R9: internal level_kernel rebuilt like the leaf: 64 parents/block, 512 thr
//     (8 waves), wave owns 16 cols per gate in ALL phases; x+h_sum in swizzled
//     LDS; fx->fc in-place in 32KB LDS f32; 176 MFMA/wave. Leaf = R8.

#define HID 128

typedef unsigned short u16;
typedef __attribute__((ext_vector_type(8))) short short8;
typedef __attribute__((ext_vector_type(4))) float floatx4;

__device__ __forceinline__ float bf2f(u16 u) {
  union { unsigned int u; float f; } v; v.u = ((unsigned int)u) << 16; return v.f;
}
__device__ __forceinline__ u16 f2bf(float f) {
  union { float f; unsigned int u; } v; v.f = f;
  unsigned int r = v.u + 0x7FFFu + ((v.u >> 16) & 1u);
  return (u16)(r >> 16);
}
__device__ __forceinline__ short8 f2bf8(float4 f0, float4 f1) {
  short8 s;
  s[0] = (short)f2bf(f0.x); s[1] = (short)f2bf(f0.y);
  s[2] = (short)f2bf(f0.z); s[3] = (short)f2bf(f0.w);
  s[4] = (short)f2bf(f1.x); s[5] = (short)f2bf(f1.y);
  s[6] = (short)f2bf(f1.z); s[7] = (short)f2bf(f1.w);
  return s;
}
__device__ __forceinline__ float sigm(float x) {
  return __builtin_amdgcn_rcpf(1.0f + __expf(-x));
}
__device__ __forceinline__ float tanh_fast(float x) {
  float ax = fabsf(x);
  float e = __expf(2.0f * ax);
  float t = 1.0f - 2.0f * __builtin_amdgcn_rcpf(e + 1.0f);
  return copysignf(t, x);
}

__global__ void prep_weights(const float* __restrict__ Wix, const float* __restrict__ Wih,
                             const float* __restrict__ Wfx, const float* __restrict__ Wfh,
                             const float* __restrict__ Wox, const float* __restrict__ Woh,
                             const float* __restrict__ Wux, const float* __restrict__ Wuh,
                             u16* __restrict__ Wcat, u16* __restrict__ Wfxb, u16* __restrict__ Wfhb)
{
  int t = blockIdx.x * 256 + threadIdx.x;
  if (t < 98304) {                 // Wcat: 384 rows x 256 k
    int nrow = t >> 8, k = t & 255;
    int gate = nrow >> 7, r = nrow & 127;
    float v;
    if (k < 128) {
      const float* W = (gate == 0) ? Wix : (gate == 1) ? Wox : Wux;
      v = W[r * 128 + k];
    } else {
      const float* W = (gate == 0) ? Wih : (gate == 1) ? Woh : Wuh;
      v = W[r * 128 + (k - 128)];
    }
    Wcat[t] = f2bf(v);
  } else if (t < 98304 + 16384) {
    int i = t - 98304;
    Wfxb[i] = f2bf(Wfx[i]);
  } else if (t < 98304 + 32768) {
    int i = t - 98304 - 16384;
    Wfhb[i] = f2bf(Wfh[i]);
  }
}

// ---------------- Leaf kernel: M=64/block, 8 waves (unchanged R8) ----------------
__global__ __launch_bounds__(512, 2)
void leaf_kernel(const float* __restrict__ embeds,
                 const u16* __restrict__ Wcat,
                 const float* __restrict__ bix, const float* __restrict__ box,
                 const float* __restrict__ bux,
                 u16* __restrict__ h_all, float* __restrict__ c_all,
                 int node_off)
{
  __shared__ char smem[16384];           // 64 rows x 256 B (bf16), XOR-swizzled
  u16* sx = (u16*)smem;

  const int tid  = threadIdx.x;
  const int wave = tid >> 6;             // 0..7
  const int lane = tid & 63;
  const int lg   = lane >> 4;
  const int ln   = lane & 15;
  const int pbase = blockIdx.x * 64;

  {
    int row = tid >> 3;
    int k0  = (tid & 7) * 16;            // float index
    const float* src = embeds + (size_t)(node_off + pbase + row) * HID + k0;
    unsigned sw = ((unsigned)(row & 7)) << 4;
    char* dst = (char*)sx + row * 256;
    float4 f0 = *(const float4*)src;
    float4 f1 = *(const float4*)(src + 4);
    float4 f2 = *(const float4*)(src + 8);
    float4 f3 = *(const float4*)(src + 12);
    *(short8*)(dst + (((unsigned)(k0 * 2)) ^ sw))      = f2bf8(f0, f1);
    *(short8*)(dst + (((unsigned)(k0 * 2 + 16)) ^ sw)) = f2bf8(f2, f3);
  }

  const int col = wave * 16 + ln;
  const float bi = bix[col], bo = box[col], bu = bux[col];

  __syncthreads();

  floatx4 acc[4][3] = {};
#pragma unroll
  for (int kt = 0; kt < 4; ++kt) {
    short8 a[4];
#pragma unroll
    for (int m = 0; m < 4; ++m) {
      int row = m * 16 + ln;
      unsigned sw = ((unsigned)(row & 7)) << 4;
      a[m] = *(const short8*)((char*)sx + row * 256 +
                              (((unsigned)((kt * 32 + lg * 8) * 2)) ^ sw));
    }
#pragma unroll
    for (int g = 0; g < 3; ++g) {
      int NT = g * 8 + wave;
      short8 b = *(const short8*)(Wcat + (size_t)(NT * 16 + ln) * 256 + kt * 32 + lg * 8);
#pragma unroll
      for (int m = 0; m < 4; ++m)
        acc[m][g] = __builtin_amdgcn_mfma_f32_16x16x32_bf16(a[m], b, acc[m][g], 0, 0, 0);
    }
  }

#pragma unroll
  for (int m = 0; m < 4; ++m)
#pragma unroll
    for (int r = 0; r < 4; ++r) {
      int row = m * 16 + lg * 4 + r;
      float iv = sigm(acc[m][0][r] + bi);
      float ov = sigm(acc[m][1][r] + bo);
      float uv = tanh_fast(acc[m][2][r] + bu);
      float cv = iv * uv;
      float hv = ov * tanh_fast(cv);
      size_t gidx = (size_t)(node_off + pbase + row) * HID + col;
      c_all[gidx] = cv;
      h_all[gidx] = f2bf(hv);
    }
}

// ---------------- Internal kernel: 64 parents/block, 8 waves ----------------
// LDS: sx 16KB (x, swz bf16) | s_hsum 16KB (swz bf16) | s_f 32KB (f32 fx->fc)
__global__ __launch_bounds__(512, 2)
void level_kernel(const float* __restrict__ embeds,
                  const u16* __restrict__ Wcat,
                  const u16* __restrict__ Wfxb,
                  const u16* __restrict__ Wfhb,
                  const float* __restrict__ bix, const float* __restrict__ bfx,
                  const float* __restrict__ box, const float* __restrict__ bux,
                  u16* __restrict__ h_all, float* __restrict__ c_all,
                  int n, int node_off, int child_off)
{
  extern __shared__ char smem[];
  u16*   sx     = (u16*)smem;              // 64 x 256B swizzled bf16
  u16*   s_hsum = (u16*)(smem + 16384);    // 64 x 256B swizzled bf16
  float* s_f    = (float*)(smem + 32768);  // 64 x 128 f32: fx, then fc in-place

  const int tid  = threadIdx.x;
  const int wave = tid >> 6;               // 0..7
  const int lane = tid & 63;
  const int lg   = lane >> 4;
  const int ln   = lane & 15;
  const int pbase = blockIdx.x * 64;
  const int cbase = child_off + 4 * pbase;
  const int col  = wave * 16 + ln;         // within-gate column owned by lane

  // ---- stage x: 64 x 128 ----
  {
    int row = tid >> 3;
    int k0  = (tid & 7) * 16;
    const float* src = embeds + (size_t)(node_off + pbase + row) * HID + k0;
    unsigned sw = ((unsigned)(row & 7)) << 4;
    char* dst = (char*)sx + row * 256;
    float4 f0 = *(const float4*)src;
    float4 f1 = *(const float4*)(src + 4);
    float4 f2 = *(const float4*)(src + 8);
    float4 f3 = *(const float4*)(src + 12);
    *(short8*)(dst + (((unsigned)(k0 * 2)) ^ sw))      = f2bf8(f0, f1);
    *(short8*)(dst + (((unsigned)(k0 * 2 + 16)) ^ sw)) = f2bf8(f2, f3);
  }

  // ---- h_sum: thread -> parent tid>>3, 16 cols chunk tid&7 ----
  {
    int p = tid >> 3, cg = tid & 7;
    const u16* ch = h_all + (size_t)(cbase + 4 * p) * HID + cg * 16;
    float hs[16];
#pragma unroll
    for (int j = 0; j < 16; ++j) hs[j] = 0.f;
#pragma unroll
    for (int b = 0; b < 4; ++b) {
      short8 v0 = *(const short8*)(ch + (size_t)b * HID);
      short8 v1 = *(const short8*)(ch + (size_t)b * HID + 8);
#pragma unroll
      for (int j = 0; j < 8; ++j) {
        hs[j]     += bf2f((u16)v0[j]);
        hs[8 + j] += bf2f((u16)v1[j]);
      }
    }
    short8 o0, o1;
#pragma unroll
    for (int j = 0; j < 8; ++j) { o0[j] = (short)f2bf(hs[j]); o1[j] = (short)f2bf(hs[8 + j]); }
    unsigned sw = ((unsigned)(p & 7)) << 4;
    *(short8*)((char*)s_hsum + p * 256 + ((cg * 32) ^ sw))      = o0;
    *(short8*)((char*)s_hsum + p * 256 + ((cg * 32 + 16) ^ sw)) = o1;
  }

  __syncthreads();

  // ---- fx GEMM: 64 parents x 16 cols (wave's slice), K=128; A from sx ----
  {
    floatx4 accx[4] = {};
#pragma unroll
    for (int kt = 0; kt < 4; ++kt) {
      short8 b = *(const short8*)(Wfxb + (size_t)(wave * 16 + ln) * HID + kt * 32 + lg * 8);
#pragma unroll
      for (int m = 0; m < 4; ++m) {
        int row = m * 16 + ln;
        unsigned sw = ((unsigned)(row & 7)) << 4;
        short8 a = *(const short8*)((char*)sx + row * 256 +
                                    (((unsigned)((kt * 32 + lg * 8) * 2)) ^ sw));
        accx[m] = __builtin_amdgcn_mfma_f32_16x16x32_bf16(a, b, accx[m], 0, 0, 0);
      }
    }
#pragma unroll
    for (int m = 0; m < 4; ++m)
#pragma unroll
      for (int r = 0; r < 4; ++r)
        s_f[(m * 16 + lg * 4 + r) * HID + col] = accx[m][r];
  }

  // ---- fh GEMM: 256 children x 16 cols (wave's slice), K=128 ----
  floatx4 accf[16] = {};
  {
    const u16* chb = h_all + (size_t)cbase * HID;
#pragma unroll
    for (int kt = 0; kt < 4; ++kt) {
      short8 b = *(const short8*)(Wfhb + (size_t)(wave * 16 + ln) * HID + kt * 32 + lg * 8);
#pragma unroll
      for (int m = 0; m < 16; ++m) {
        short8 a = *(const short8*)(chb + (size_t)(m * 16 + ln) * HID + kt * 32 + lg * 8);
        accf[m] = __builtin_amdgcn_mfma_f32_16x16x32_bf16(a, b, accf[m], 0, 0, 0);
      }
    }
  }

  __syncthreads();   // all fx writes visible

  // ---- combine: f = sigm(fx+bfx+fh); fc = sum_r f*c_child; fx -> fc in place.
  // Lane's accf[m][r] holds fh[child = m*16+lg*4+r][col]; those 4 children all
  // belong to parent p = m*4+lg, so fc is an in-lane reduction.
  {
    float bf = bfx[col];
#pragma unroll
    for (int m = 0; m < 16; ++m) {
      int p = m * 4 + lg;
      float fxv = s_f[p * HID + col] + bf;
      const float* crow = c_all + (size_t)(cbase + m * 16 + lg * 4) * HID + col;
      float fc = 0.f;
#pragma unroll
      for (int r = 0; r < 4; ++r)
        fc += sigm(fxv + accf[m][r]) * crow[(size_t)r * HID];
      s_f[p * HID + col] = fc;   // same element this thread just read: safe
    }
  }

  __syncthreads();   // all fc writes visible

  // ---- main GEMM: [x | h_sum] @ Wcat^T, 64 x 3 gates x 16 cols, K=256 ----
  floatx4 acc[4][3] = {};
#pragma unroll
  for (int kt = 0; kt < 8; ++kt) {
    short8 a[4];
#pragma unroll
    for (int m = 0; m < 4; ++m) {
      int row = m * 16 + ln;
      unsigned sw = ((unsigned)(row & 7)) << 4;
      const char* base = (kt < 4) ? (const char*)sx : (const char*)s_hsum;
      int kb = ((kt & 3) * 32 + lg * 8) * 2;
      a[m] = *(const short8*)(base + row * 256 + (((unsigned)kb) ^ sw));
    }
#pragma unroll
    for (int g = 0; g < 3; ++g) {
      short8 b = *(const short8*)(Wcat + (size_t)((g * 8 + wave) * 16 + ln) * 256 + kt * 32 + lg * 8);
#pragma unroll
      for (int m = 0; m < 4; ++m)
        acc[m][g] = __builtin_amdgcn_mfma_f32_16x16x32_bf16(a[m], b, acc[m][g], 0, 0, 0);
    }
  }

  // ---- epilogue ----
  {
    float bi = bix[col], bo = box[col], bu = bux[col];
#pragma unroll
    for (int m = 0; m < 4; ++m)
#pragma unroll
      for (int r = 0; r < 4; ++r) {
        int row = m * 16 + lg * 4 + r;
        if (pbase + row < n) {
          float iv = sigm(acc[m][0][r] + bi);
          float ov = sigm(acc[m][1][r] + bo);
          float uv = tanh_fast(acc[m][2][r] + bu);
          float fc = s_f[row * HID + col];
          float cv = iv * uv + fc;
          float hv = ov * tanh_fast(cv);
          size_t gidx = (size_t)(node_off + pbase + row) * HID + col;
          c_all[gidx] = cv;
          h_all[gidx] = f2bf(hv);
        }
      }
  }
}

__global__ void out_kernel(const u16* __restrict__ h_all, const float* __restrict__ Wout,
                           const float* __restrict__ bout, float* __restrict__ out)
{
  int t = threadIdx.x;
  if (t < 80) {                 // 16 roots x 5 labels
    int row = t / 5, lbl = t - row * 5;
    float s = bout[lbl];
    for (int k = 0; k < 128; ++k)
      s += bf2f(h_all[row * 128 + k]) * Wout[lbl * 128 + k];
    out[t] = s;
  }
}

extern "C" void kernel_launch(void* const* d_in, const int* in_sizes, int n_in,
                              void* d_out, int out_size, void* d_ws, size_t ws_size,
                              hipStream_t stream)
{
  const float* embeds = (const float*)d_in[0];
  const float* Wix = (const float*)d_in[1];
  const float* bix = (const float*)d_in[2];
  const float* Wih = (const float*)d_in[3];
  const float* Wfx = (const float*)d_in[4];
  const float* bfx = (const float*)d_in[5];
  const float* Wfh = (const float*)d_in[6];
  const float* Wox = (const float*)d_in[7];
  const float* box = (const float*)d_in[8];
  const float* Woh = (const float*)d_in[9];
  const float* Wux = (const float*)d_in[10];
  const float* bux = (const float*)d_in[11];
  const float* Wuh = (const float*)d_in[12];
  const float* Wout = (const float*)d_in[13];
  const float* bout = (const float*)d_in[14];

  static const int counts[8]  = {16, 64, 256, 1024, 4096, 16384, 65536, 262144};
  static const int offsets[9] = {0, 16, 80, 336, 1360, 5456, 21840, 87376, 349520};

  char* ws = (char*)d_ws;
  u16*   h_all = (u16*)ws;                                   // 89,477,120 B
  float* c_all = (float*)(ws + 89477120);                    // 178,954,240 B
  u16*   Wcat  = (u16*)(ws + 89477120 + 178954240);          // 384*256*2
  u16*   Wfxb  = Wcat + 384 * 256;
  u16*   Wfhb  = Wfxb + 128 * 128;

  prep_weights<<<512, 256, 0, stream>>>(Wix, Wih, Wfx, Wfh, Wox, Woh, Wux, Wuh,
                                        Wcat, Wfxb, Wfhb);

  // level 7 (leaves): M=64/block, 8 waves
  leaf_kernel<<<262144 / 64, 512, 0, stream>>>(
      embeds, Wcat, bix, box, bux, h_all, c_all, 87376);

  // levels 6..0 (internal): 64 parents/block
  for (int l = 6; l >= 0; --l) {
    int n = counts[l];
    int grid = (n + 63) / 64;
    level_kernel<<<grid, 512, 65536, stream>>>(
        embeds, Wcat, Wfxb, Wfhb, bix, bfx, box, bux,
        h_all, c_all, n, offsets[l], offsets[l + 1]);
  }

  out_kernel<<<1, 128, 0, stream>>>(h_all, Wout, bout, (float*)d_out);
}